// Round 15
// baseline (152.145 us; speedup 1.0000x reference)
//
#include <hip/hip_runtime.h>
#include <stdint.h>

// RNN1: B=4096,T=256,E=27,H=64.
// a_{t+1} = tanh(a_t @ Waa^T + x_t @ Wax^T + ba), x_t = word[:,t-1,:] (0 at t=0)
// y[:,t,:] = a_{t+1} @ Wy^T + by
//
// Round 15 = r12 base (152us, absmax 0.0078125) + ONE change: y LDS write
// deferred one step via yp regs (the ds_write no longer stalls on the fresh
// y-MFMA result; it writes data computed a full step earlier).
// r14's bisect verdict: pkrtz (RTZ) on the STATE pack caused 0.297 error --
// RTZ's one-sided bias (~2.4e-4) is amplified coherently by the recurrence
// Jacobian (||Waa||_2 ~ 1.68); RNE's zero-mean errors random-walk. State pack
// is back to RNE pkf16 (r12-exact). x-pack keeps pkrtz (one linear term, no
// feedback). x LDS ring kept verbatim from r12 (r13's x-path rewrite had an
// independent NaN bug; not re-attempted).
//
// TRANSPOSED per-wave design (r4-r12): wave owns 16 batch rows, full H=64
// chain; state^T = Waa @ a^T, weights as A (rows m, k pre-permuted by sigma),
// state as B (n=batch). D layout (n=lane&15, m=4*lg+reg) IS the next step's
// sigma B-frag -> zero-cost feedback. sigma_f(lg,j)=(j<4?4lg+j:12+4lg+j)+32f.
// f16 single-term state (r12-validated); zp = ba + WX*x_t pre-hoisted.

#define B_ 4096
#define T_ 256
#define E_ 27
#define H_ 64
#define WROW_ (H_ + E_)  // 91

typedef _Float16 f16x8 __attribute__((ext_vector_type(8)));
typedef float f32x4 __attribute__((ext_vector_type(4)));
typedef unsigned int u32x4 __attribute__((ext_vector_type(4)));

struct __attribute__((packed)) f4a { float v[4]; };  // 4B-aligned global float4

// RNE f32->f16 pair pack (state + weight prep; r12-validated numerics).
static __device__ __forceinline__ unsigned pkf16(float a, float b) {
  _Float16 ha = (_Float16)a, hb = (_Float16)b;
  unsigned short ua = __builtin_bit_cast(unsigned short, ha);
  unsigned short ub = __builtin_bit_cast(unsigned short, hb);
  return (unsigned)ua | ((unsigned)ub << 16);
}
// RTZ packed f32x2->f16x2, 1 instr (x-path ONLY: no feedback amplification).
static __device__ __forceinline__ unsigned pkrtz(float a, float b) {
  unsigned r;
  asm("v_cvt_pkrtz_f16_f32 %0, %1, %2" : "=v"(r) : "v"(a), "v"(b));
  return r;
}
static __device__ __forceinline__ float fast_tanh(float z) {
  // tanh(z) = 1 - 2/(exp(2z)+1); exp->inf / ->0 limits give +/-1 correctly
  float e = __expf(2.0f * z);
  float r = __builtin_amdgcn_rcpf(e + 1.0f);
  return __builtin_fmaf(-2.0f, r, 1.0f);
}
static __device__ __forceinline__ f32x4 MFH(u32x4 a, u32x4 b, f32x4 c) {
  return __builtin_amdgcn_mfma_f32_16x16x32_f16(
      __builtin_bit_cast(f16x8, a), __builtin_bit_cast(f16x8, b), c, 0, 0, 0);
}

__global__ __launch_bounds__(64)
__attribute__((amdgpu_waves_per_eu(1, 1))) void rnn_fused(
    const float* __restrict__ word, const float* __restrict__ Wa,
    const float* __restrict__ ba, const float* __restrict__ Wy,
    const float* __restrict__ by, float* __restrict__ out) {
  // x ring: slot s holds x for step t (t%8==s) = word[:,t-1,:]; 36-pad ->
  // worst LDS aliasing 2-way (free). cols 28..35 stay zero forever.
  __shared__ __align__(16) float xs[8][16][36];
  __shared__ __align__(16) float ys[4][16][36];

  const int lane = threadIdx.x;
  const int p16 = lane & 15;  // batch row within group (n) / weight row (m)
  const int lg = lane >> 4;   // k-slot group / step-within-group for staging
  const int rb = (int)blockIdx.x * 16;

  const float* const wbase = word + (size_t)(rb + p16) * (T_ * E_);
  float* const obase = out + (size_t)(rb + p16) * (T_ * E_);

  {  // zero xs once (single wave: ordering vs later ds ops is automatic)
    float* xz = &xs[0][0][0];
    for (int i = lane; i < 8 * 16 * 36; i += 64) xz[i] = 0.f;
  }

  // ---- weight fragments (f16), pre-permuted by sigma (r12) ----
  u32x4 WH[4][2], WX[4], WY[2][2];
  f32x4 BAv[4], BYv[2];
#pragma unroll
  for (int mt = 0; mt < 4; ++mt) {
    const float* base = Wa + (16 * mt + p16) * WROW_;
#pragma unroll
    for (int f = 0; f < 2; ++f) {
#pragma unroll
      for (int v = 0; v < 4; ++v) {
        const int j = 2 * v;
        const int c = ((j < 4) ? (4 * lg + j) : (12 + 4 * lg + j)) + 32 * f;
        WH[mt][f][v] = pkf16(base[c], base[c + 1]);
      }
    }
#pragma unroll
    for (int v = 0; v < 4; ++v) {  // Wax, natural k = e; cols >=27 zero
      const int e0 = 8 * lg + 2 * v, e1 = e0 + 1;
      const float w0 = (e0 < E_) ? base[H_ + e0] : 0.f;
      const float w1 = (e1 < E_) ? base[H_ + e1] : 0.f;
      WX[mt][v] = pkf16(w0, w1);
    }
  }
#pragma unroll
  for (int my = 0; my < 2; ++my) {
    const int e = 16 * my + p16;
    const bool valid = (e < E_);
    const float* rp = Wy + e * H_;
#pragma unroll
    for (int f = 0; f < 2; ++f) {
#pragma unroll
      for (int v = 0; v < 4; ++v) {
        const int j = 2 * v;
        const int c = ((j < 4) ? (4 * lg + j) : (12 + 4 * lg + j)) + 32 * f;
        const float w0 = valid ? rp[c] : 0.f;
        const float w1 = valid ? rp[c + 1] : 0.f;
        WY[my][f][v] = pkf16(w0, w1);
      }
    }
  }
#pragma unroll
  for (int mt = 0; mt < 4; ++mt) {
    f32x4 t;
#pragma unroll
    for (int r = 0; r < 4; ++r) t[r] = ba[16 * mt + 4 * lg + r];
    BAv[mt] = t;
  }
#pragma unroll
  for (int my = 0; my < 2; ++my) {
    f32x4 t;
#pragma unroll
    for (int r = 0; r < 4; ++r) {
      const int e = 16 * my + 4 * lg + r;
      t[r] = (e < E_) ? by[e] : 0.f;
    }
    BYv[my] = t;
  }

  // ---- x staging, double-buffered regs (r9/r12-validated) ----
  f32x4 Rg[2][7];
#define X_ISSUE(ts, P)                                                      \
  {                                                                         \
    const int st_ = (ts) + lg;                                              \
    if (st_ >= 1 && st_ < T_) {                                             \
      const float* p_ = wbase + (st_ - 1) * E_;                             \
      _Pragma("unroll") for (int c = 0; c < 7; ++c) {                       \
        asm volatile("global_load_dwordx4 %0, %1, off"                      \
                     : "=v"(Rg[P][c]) : "v"(p_ + 4 * c) : "memory");        \
      }                                                                     \
    }                                                                       \
  }
#define X_WRITE(ts, P)                                                      \
  {                                                                         \
    asm volatile("s_waitcnt vmcnt(0)" ::: "memory");                        \
    __builtin_amdgcn_sched_barrier(0);                                      \
    const int st_ = (ts) + lg;                                              \
    if (st_ >= 1 && st_ < T_) {                                             \
      float* d_ = &xs[st_ & 7][p16][0];                                     \
      _Pragma("unroll") for (int c = 0; c < 7; ++c)                         \
        *(f32x4*)(d_ + 4 * c) = Rg[P][c];                                   \
    }                                                                       \
    asm volatile("s_waitcnt lgkmcnt(0)" ::: "memory");                      \
    __builtin_amdgcn_sched_barrier(0);                                      \
  }
#define Y_FLUSH(tb)                                                         \
  {                                                                         \
    const float* s_ = &ys[lg][p16][0];                                      \
    float* d_ = obase + ((tb) + lg) * E_;                                   \
    _Pragma("unroll") for (int c = 0; c < 6; ++c) {                         \
      f32x4 v_ = *(const f32x4*)(s_ + 4 * c);                               \
      f4a o_;                                                               \
      o_.v[0] = v_[0]; o_.v[1] = v_[1]; o_.v[2] = v_[2]; o_.v[3] = v_[3];   \
      *(f4a*)(d_ + 4 * c) = o_;                                             \
    }                                                                       \
    f32x4 v6_ = *(const f32x4*)(s_ + 24);                                   \
    d_[24] = v6_[0]; d_[25] = v6_[1]; d_[26] = v6_[2];                      \
  }

  // ---- prologue: stage steps 1..3, issue 4..7; preload xc = x_1 ----
  X_ISSUE(0, 0);
  X_WRITE(0, 0);
  X_ISSUE(4, 1);
  f32x4 xc0, xc1;
  {
    const float* xp = &xs[1][p16][8 * lg];
    xc0 = *(const f32x4*)xp;
    xc1 = *(const f32x4*)(xp + 4);
  }

  // ---- loop-carried: sF (f16 state) = 0; zp = ba + WX*x_t (x_0=0 -> ba);
  // yp = previous step's y (deferred LDS write) ----
  u32x4 sF0 = {0u, 0u, 0u, 0u}, sF1 = sF0;
  f32x4 zp0 = BAv[0], zp1 = BAv[1], zp2 = BAv[2], zp3 = BAv[3];
  f32x4 yp0 = {0.f, 0.f, 0.f, 0.f}, yp1 = yp0;
  const f32x4 zf4 = {0.f, 0.f, 0.f, 0.f};

#define STEP(t)                                                               \
  {                                                                           \
    /* critical path: 8 parallel MFMAs -> add -> tanh -> RNE f16 pack */      \
    f32x4 a0 = MFH(WH[0][0], sF0, zp0);                                       \
    f32x4 a1 = MFH(WH[1][0], sF0, zp1);                                       \
    f32x4 a2 = MFH(WH[2][0], sF0, zp2);                                       \
    f32x4 a3 = MFH(WH[3][0], sF0, zp3);                                       \
    f32x4 b0 = MFH(WH[0][1], sF1, zf4);                                       \
    f32x4 b1 = MFH(WH[1][1], sF1, zf4);                                       \
    f32x4 b2 = MFH(WH[2][1], sF1, zf4);                                       \
    f32x4 b3 = MFH(WH[3][1], sF1, zf4);                                       \
    /* deferred y write: step t-1's y has a full step of slack */             \
    if ((t) > 0) {                                                            \
      *(f32x4*)&ys[((t)-1) & 3][p16][4 * lg] = yp0;                           \
      *(f32x4*)&ys[((t)-1) & 3][p16][16 + 4 * lg] = yp1;                      \
    }                                                                         \
    const f32x4 z0 = a0 + b0;                                                 \
    const f32x4 z1 = a1 + b1;                                                 \
    float tv[16];                                                             \
    _Pragma("unroll") for (int r = 0; r < 4; ++r) tv[r] = fast_tanh(z0[r]);   \
    _Pragma("unroll") for (int r = 0; r < 4; ++r) tv[4 + r] = fast_tanh(z1[r]);\
    sF0[0] = pkf16(tv[0], tv[1]);                                             \
    sF0[1] = pkf16(tv[2], tv[3]);                                             \
    sF0[2] = pkf16(tv[4], tv[5]);                                             \
    sF0[3] = pkf16(tv[6], tv[7]);                                             \
    const f32x4 z2 = a2 + b2;                                                 \
    const f32x4 z3 = a3 + b3;                                                 \
    _Pragma("unroll") for (int r = 0; r < 4; ++r) tv[8 + r] = fast_tanh(z2[r]);\
    _Pragma("unroll") for (int r = 0; r < 4; ++r) tv[12 + r] = fast_tanh(z3[r]);\
    sF1[0] = pkf16(tv[8], tv[9]);                                             \
    sF1[1] = pkf16(tv[10], tv[11]);                                           \
    sF1[2] = pkf16(tv[12], tv[13]);                                           \
    sF1[3] = pkf16(tv[14], tv[15]);                                           \
    /* off-path: x_{t+1} pack (RTZ ok: no feedback) + zp for next step */     \
    u32x4 xfn;                                                                \
    xfn[0] = pkrtz(xc0[0], xc0[1]);                                           \
    xfn[1] = pkrtz(xc0[2], xc0[3]);                                           \
    xfn[2] = pkrtz(xc1[0], xc1[1]);                                           \
    xfn[3] = pkrtz(xc1[2], xc1[3]);                                           \
    zp0 = MFH(WX[0], xfn, BAv[0]);                                            \
    zp1 = MFH(WX[1], xfn, BAv[1]);                                            \
    zp2 = MFH(WX[2], xfn, BAv[2]);                                            \
    zp3 = MFH(WX[3], xfn, BAv[3]);                                            \
    if ((t) + 2 < T_) { /* prefetch x_{t+2} from ring (full step of slack) */ \
      const float* xp_ = &xs[((t) + 2) & 7][p16][8 * lg];                     \
      xc0 = *(const f32x4*)xp_;                                               \
      xc1 = *(const f32x4*)(xp_ + 4);                                         \
    }                                                                         \
    /* y for step t into yp (uses NEW state; written to LDS next step) */     \
    yp0 = MFH(WY[0][1], sF1, MFH(WY[0][0], sF0, BYv[0]));                     \
    yp1 = MFH(WY[1][1], sF1, MFH(WY[1][0], sF0, BYv[1]));                     \
  }

#define GROUP(t0, PW, PI)                                                     \
  {                                                                           \
    /* AGPR pins: weights resident in AGPRs; biases in VGPRs (r6 lesson). */  \
    _Pragma("unroll") for (int mt = 0; mt < 4; ++mt) {                        \
      asm volatile("" : "+a"(WH[mt][0]), "+a"(WH[mt][1]), "+a"(WX[mt]));      \
    }                                                                         \
    asm volatile("" : "+a"(WY[0][0]), "+a"(WY[0][1]), "+a"(WY[1][0]),         \
                      "+a"(WY[1][1]));                                        \
    asm volatile("" : "+v"(BAv[0]), "+v"(BAv[1]), "+v"(BAv[2]), "+v"(BAv[3]), \
                      "+v"(BYv[0]), "+v"(BYv[1]));                            \
    X_WRITE((t0) + 4, PW); /* stage steps t0+4..t0+7 (issued last group) */   \
    X_ISSUE((t0) + 8, PI); /* issue next group into the OTHER buffer */       \
    STEP(t0);              /* writes y_{t0-1} -> slot 3 */                    \
    if ((t0) > 0) Y_FLUSH((t0)-4); /* flush steps t0-4..t0-1 */               \
    STEP((t0) + 1);                                                           \
    STEP((t0) + 2);                                                           \
    STEP((t0) + 3);                                                           \
  }

  for (int t0 = 0; t0 < T_; t0 += 8) {
    GROUP(t0, 1, 0);      // write R1 (issued in prologue / prev odd group)
    GROUP(t0 + 4, 0, 1);  // write R0, issue R1
  }
  // epilogue: y_255 into slot 3, then flush the last group
  *(f32x4*)&ys[3][p16][4 * lg] = yp0;
  *(f32x4*)&ys[3][p16][16 + 4 * lg] = yp1;
  Y_FLUSH(T_ - 4);
#undef GROUP
#undef STEP
#undef X_ISSUE
#undef X_WRITE
#undef Y_FLUSH
}

extern "C" void kernel_launch(void* const* d_in, const int* in_sizes, int n_in,
                              void* d_out, int out_size, void* d_ws,
                              size_t ws_size, hipStream_t stream) {
  const float* word = (const float*)d_in[0];
  const float* Wa = (const float*)d_in[1];
  const float* ba = (const float*)d_in[2];
  const float* Wy = (const float*)d_in[3];
  const float* by = (const float*)d_in[4];
  float* out = (float*)d_out;
  rnn_fused<<<dim3(B_ / 16), dim3(64), 0, stream>>>(word, Wa, ba, Wy, by, out);
}

// Round 16
// 151.169 us; speedup vs baseline: 1.0065x; 1.0065x over previous
//
#include <hip/hip_runtime.h>
#include <stdint.h>

// RNN1: B=4096,T=256,E=27,H=64.
// a_{t+1} = tanh(a_t @ Waa^T + x_t @ Wax^T + ba), x_t = word[:,t-1,:] (0 at t=0)
// y[:,t,:] = a_{t+1} @ Wy^T + by
//
// Round 16 = r15 (152us, absmax 0.0078125) with STEP re-SCHEDULED only
// (numerics bit-identical; tests hypothesis H1 "source staggering serializes
// the tanh region + leaves the 78-cyc MFMA dep window empty"):
//  - all 8 state MFMAs issue first; their latency shadow is filled with ALL
//    independent work: y ds_write (prev step), x pack, the 4 zp MFMAs
//    (moved from post-tanh; zn->zp rotate), the x LDS prefetch.
//  - then 4 z-adds, then ALL 16 tanh chains flat (no packs between groups),
//    then all 8 RNE packs, then the 2x2 y MFMAs.
// If neutral -> H2 (TRANS-pipe issue floor, 32 exp/rcp per step) and round 17
// goes to a 1-trans-per-value rational tanh.
//
// TRANSPOSED per-wave design (r4-r15): wave owns 16 batch rows, full H=64
// chain; state^T = Waa @ a^T, weights as A (rows m, k pre-permuted by sigma),
// state as B (n=batch). D layout (n=lane&15, m=4*lg+reg) IS the next step's
// sigma B-frag -> zero-cost feedback. sigma_f(lg,j)=(j<4?4lg+j:12+4lg+j)+32f.
// f16 single-term state (r12); zp = ba + WX*x_t pre-hoisted one step.

#define B_ 4096
#define T_ 256
#define E_ 27
#define H_ 64
#define WROW_ (H_ + E_)  // 91

typedef _Float16 f16x8 __attribute__((ext_vector_type(8)));
typedef float f32x4 __attribute__((ext_vector_type(4)));
typedef unsigned int u32x4 __attribute__((ext_vector_type(4)));

struct __attribute__((packed)) f4a { float v[4]; };  // 4B-aligned global float4

// RNE f32->f16 pair pack (state + weight prep; r12-validated numerics).
static __device__ __forceinline__ unsigned pkf16(float a, float b) {
  _Float16 ha = (_Float16)a, hb = (_Float16)b;
  unsigned short ua = __builtin_bit_cast(unsigned short, ha);
  unsigned short ub = __builtin_bit_cast(unsigned short, hb);
  return (unsigned)ua | ((unsigned)ub << 16);
}
// RTZ packed f32x2->f16x2, 1 instr (x-path ONLY: no feedback amplification;
// r14 lesson: NEVER biased rounding on the recurrent state).
static __device__ __forceinline__ unsigned pkrtz(float a, float b) {
  unsigned r;
  asm("v_cvt_pkrtz_f16_f32 %0, %1, %2" : "=v"(r) : "v"(a), "v"(b));
  return r;
}
static __device__ __forceinline__ float fast_tanh(float z) {
  // tanh(z) = 1 - 2/(exp(2z)+1); exp->inf / ->0 limits give +/-1 correctly
  float e = __expf(2.0f * z);
  float r = __builtin_amdgcn_rcpf(e + 1.0f);
  return __builtin_fmaf(-2.0f, r, 1.0f);
}
static __device__ __forceinline__ f32x4 MFH(u32x4 a, u32x4 b, f32x4 c) {
  return __builtin_amdgcn_mfma_f32_16x16x32_f16(
      __builtin_bit_cast(f16x8, a), __builtin_bit_cast(f16x8, b), c, 0, 0, 0);
}

__global__ __launch_bounds__(64)
__attribute__((amdgpu_waves_per_eu(1, 1))) void rnn_fused(
    const float* __restrict__ word, const float* __restrict__ Wa,
    const float* __restrict__ ba, const float* __restrict__ Wy,
    const float* __restrict__ by, float* __restrict__ out) {
  // x ring: slot s holds x for step t (t%8==s) = word[:,t-1,:]; 36-pad ->
  // worst LDS aliasing 2-way (free). cols 28..35 stay zero forever.
  __shared__ __align__(16) float xs[8][16][36];
  __shared__ __align__(16) float ys[4][16][36];

  const int lane = threadIdx.x;
  const int p16 = lane & 15;  // batch row within group (n) / weight row (m)
  const int lg = lane >> 4;   // k-slot group / step-within-group for staging
  const int rb = (int)blockIdx.x * 16;

  const float* const wbase = word + (size_t)(rb + p16) * (T_ * E_);
  float* const obase = out + (size_t)(rb + p16) * (T_ * E_);

  {  // zero xs once (single wave: ordering vs later ds ops is automatic)
    float* xz = &xs[0][0][0];
    for (int i = lane; i < 8 * 16 * 36; i += 64) xz[i] = 0.f;
  }

  // ---- weight fragments (f16), pre-permuted by sigma (r12) ----
  u32x4 WH[4][2], WX[4], WY[2][2];
  f32x4 BAv[4], BYv[2];
#pragma unroll
  for (int mt = 0; mt < 4; ++mt) {
    const float* base = Wa + (16 * mt + p16) * WROW_;
#pragma unroll
    for (int f = 0; f < 2; ++f) {
#pragma unroll
      for (int v = 0; v < 4; ++v) {
        const int j = 2 * v;
        const int c = ((j < 4) ? (4 * lg + j) : (12 + 4 * lg + j)) + 32 * f;
        WH[mt][f][v] = pkf16(base[c], base[c + 1]);
      }
    }
#pragma unroll
    for (int v = 0; v < 4; ++v) {  // Wax, natural k = e; cols >=27 zero
      const int e0 = 8 * lg + 2 * v, e1 = e0 + 1;
      const float w0 = (e0 < E_) ? base[H_ + e0] : 0.f;
      const float w1 = (e1 < E_) ? base[H_ + e1] : 0.f;
      WX[mt][v] = pkf16(w0, w1);
    }
  }
#pragma unroll
  for (int my = 0; my < 2; ++my) {
    const int e = 16 * my + p16;
    const bool valid = (e < E_);
    const float* rp = Wy + e * H_;
#pragma unroll
    for (int f = 0; f < 2; ++f) {
#pragma unroll
      for (int v = 0; v < 4; ++v) {
        const int j = 2 * v;
        const int c = ((j < 4) ? (4 * lg + j) : (12 + 4 * lg + j)) + 32 * f;
        const float w0 = valid ? rp[c] : 0.f;
        const float w1 = valid ? rp[c + 1] : 0.f;
        WY[my][f][v] = pkf16(w0, w1);
      }
    }
  }
#pragma unroll
  for (int mt = 0; mt < 4; ++mt) {
    f32x4 t;
#pragma unroll
    for (int r = 0; r < 4; ++r) t[r] = ba[16 * mt + 4 * lg + r];
    BAv[mt] = t;
  }
#pragma unroll
  for (int my = 0; my < 2; ++my) {
    f32x4 t;
#pragma unroll
    for (int r = 0; r < 4; ++r) {
      const int e = 16 * my + 4 * lg + r;
      t[r] = (e < E_) ? by[e] : 0.f;
    }
    BYv[my] = t;
  }

  // ---- x staging, double-buffered regs (r9/r12-validated) ----
  f32x4 Rg[2][7];
#define X_ISSUE(ts, P)                                                      \
  {                                                                         \
    const int st_ = (ts) + lg;                                              \
    if (st_ >= 1 && st_ < T_) {                                             \
      const float* p_ = wbase + (st_ - 1) * E_;                             \
      _Pragma("unroll") for (int c = 0; c < 7; ++c) {                       \
        asm volatile("global_load_dwordx4 %0, %1, off"                      \
                     : "=v"(Rg[P][c]) : "v"(p_ + 4 * c) : "memory");        \
      }                                                                     \
    }                                                                       \
  }
#define X_WRITE(ts, P)                                                      \
  {                                                                         \
    asm volatile("s_waitcnt vmcnt(0)" ::: "memory");                        \
    __builtin_amdgcn_sched_barrier(0);                                      \
    const int st_ = (ts) + lg;                                              \
    if (st_ >= 1 && st_ < T_) {                                             \
      float* d_ = &xs[st_ & 7][p16][0];                                     \
      _Pragma("unroll") for (int c = 0; c < 7; ++c)                         \
        *(f32x4*)(d_ + 4 * c) = Rg[P][c];                                   \
    }                                                                       \
    asm volatile("s_waitcnt lgkmcnt(0)" ::: "memory");                      \
    __builtin_amdgcn_sched_barrier(0);                                      \
  }
#define Y_FLUSH(tb)                                                         \
  {                                                                         \
    const float* s_ = &ys[lg][p16][0];                                      \
    float* d_ = obase + ((tb) + lg) * E_;                                   \
    _Pragma("unroll") for (int c = 0; c < 6; ++c) {                         \
      f32x4 v_ = *(const f32x4*)(s_ + 4 * c);                               \
      f4a o_;                                                               \
      o_.v[0] = v_[0]; o_.v[1] = v_[1]; o_.v[2] = v_[2]; o_.v[3] = v_[3];   \
      *(f4a*)(d_ + 4 * c) = o_;                                             \
    }                                                                       \
    f32x4 v6_ = *(const f32x4*)(s_ + 24);                                   \
    d_[24] = v6_[0]; d_[25] = v6_[1]; d_[26] = v6_[2];                      \
  }

  // ---- prologue: stage steps 1..3, issue 4..7; preload xc = x_1 ----
  X_ISSUE(0, 0);
  X_WRITE(0, 0);
  X_ISSUE(4, 1);
  f32x4 xc0, xc1;
  {
    const float* xp = &xs[1][p16][8 * lg];
    xc0 = *(const f32x4*)xp;
    xc1 = *(const f32x4*)(xp + 4);
  }

  // ---- loop-carried: sF (f16 state) = 0; zp = ba + WX*x_t (x_0=0 -> ba);
  // yp = previous step's y (deferred LDS write) ----
  u32x4 sF0 = {0u, 0u, 0u, 0u}, sF1 = sF0;
  f32x4 zp0 = BAv[0], zp1 = BAv[1], zp2 = BAv[2], zp3 = BAv[3];
  f32x4 yp0 = {0.f, 0.f, 0.f, 0.f}, yp1 = yp0;
  const f32x4 zf4 = {0.f, 0.f, 0.f, 0.f};

#define STEP(t)                                                               \
  {                                                                           \
    /* 1) critical MFMAs: issue all 8 */                                      \
    f32x4 a0 = MFH(WH[0][0], sF0, zp0);                                       \
    f32x4 a1 = MFH(WH[1][0], sF0, zp1);                                       \
    f32x4 a2 = MFH(WH[2][0], sF0, zp2);                                       \
    f32x4 a3 = MFH(WH[3][0], sF0, zp3);                                       \
    f32x4 b0 = MFH(WH[0][1], sF1, zf4);                                       \
    f32x4 b1 = MFH(WH[1][1], sF1, zf4);                                       \
    f32x4 b2 = MFH(WH[2][1], sF1, zf4);                                       \
    f32x4 b3 = MFH(WH[3][1], sF1, zf4);                                       \
    /* 2) fill the ~78cyc MFMA dep window with ALL independent work */        \
    if ((t) > 0) { /* deferred y write: step t-1's y */                       \
      *(f32x4*)&ys[((t)-1) & 3][p16][4 * lg] = yp0;                           \
      *(f32x4*)&ys[((t)-1) & 3][p16][16 + 4 * lg] = yp1;                      \
    }                                                                         \
    u32x4 xfn;                                                                \
    xfn[0] = pkrtz(xc0[0], xc0[1]);                                           \
    xfn[1] = pkrtz(xc0[2], xc0[3]);                                           \
    xfn[2] = pkrtz(xc1[0], xc1[1]);                                           \
    xfn[3] = pkrtz(xc1[2], xc1[3]);                                           \
    const f32x4 zn0 = MFH(WX[0], xfn, BAv[0]);  /* zp for step t+1 */         \
    const f32x4 zn1 = MFH(WX[1], xfn, BAv[1]);                                \
    const f32x4 zn2 = MFH(WX[2], xfn, BAv[2]);                                \
    const f32x4 zn3 = MFH(WX[3], xfn, BAv[3]);                                \
    if ((t) + 2 < T_) { /* prefetch x_{t+2} from ring */                      \
      const float* xp_ = &xs[((t) + 2) & 7][p16][8 * lg];                     \
      xc0 = *(const f32x4*)xp_;                                               \
      xc1 = *(const f32x4*)(xp_ + 4);                                         \
    }                                                                         \
    /* 3) consume MFMA results */                                             \
    const f32x4 z0 = a0 + b0;                                                 \
    const f32x4 z1 = a1 + b1;                                                 \
    const f32x4 z2 = a2 + b2;                                                 \
    const f32x4 z3 = a3 + b3;                                                 \
    /* 4) ALL 16 tanh chains flat (16 independent dep chains) */              \
    float tv[16];                                                             \
    _Pragma("unroll") for (int r = 0; r < 4; ++r) tv[r] = fast_tanh(z0[r]);   \
    _Pragma("unroll") for (int r = 0; r < 4; ++r) tv[4 + r] = fast_tanh(z1[r]);\
    _Pragma("unroll") for (int r = 0; r < 4; ++r) tv[8 + r] = fast_tanh(z2[r]);\
    _Pragma("unroll") for (int r = 0; r < 4; ++r) tv[12 + r] = fast_tanh(z3[r]);\
    /* 5) all 8 RNE packs */                                                  \
    sF0[0] = pkf16(tv[0], tv[1]);                                             \
    sF0[1] = pkf16(tv[2], tv[3]);                                             \
    sF0[2] = pkf16(tv[4], tv[5]);                                             \
    sF0[3] = pkf16(tv[6], tv[7]);                                             \
    sF1[0] = pkf16(tv[8], tv[9]);                                             \
    sF1[1] = pkf16(tv[10], tv[11]);                                           \
    sF1[2] = pkf16(tv[12], tv[13]);                                           \
    sF1[3] = pkf16(tv[14], tv[15]);                                           \
    /* 6) zp rotate (register rename; no copies after coalescing) */          \
    zp0 = zn0; zp1 = zn1; zp2 = zn2; zp3 = zn3;                               \
    /* 7) y for step t into yp (written to LDS next step) */                  \
    yp0 = MFH(WY[0][1], sF1, MFH(WY[0][0], sF0, BYv[0]));                     \
    yp1 = MFH(WY[1][1], sF1, MFH(WY[1][0], sF0, BYv[1]));                     \
  }

#define GROUP(t0, PW, PI)                                                     \
  {                                                                           \
    /* AGPR pins: weights resident in AGPRs; biases in VGPRs (r6 lesson). */  \
    _Pragma("unroll") for (int mt = 0; mt < 4; ++mt) {                        \
      asm volatile("" : "+a"(WH[mt][0]), "+a"(WH[mt][1]), "+a"(WX[mt]));      \
    }                                                                         \
    asm volatile("" : "+a"(WY[0][0]), "+a"(WY[0][1]), "+a"(WY[1][0]),         \
                      "+a"(WY[1][1]));                                        \
    asm volatile("" : "+v"(BAv[0]), "+v"(BAv[1]), "+v"(BAv[2]), "+v"(BAv[3]), \
                      "+v"(BYv[0]), "+v"(BYv[1]));                            \
    X_WRITE((t0) + 4, PW); /* stage steps t0+4..t0+7 (issued last group) */   \
    X_ISSUE((t0) + 8, PI); /* issue next group into the OTHER buffer */       \
    STEP(t0);              /* writes y_{t0-1} -> slot 3 */                    \
    if ((t0) > 0) Y_FLUSH((t0)-4); /* flush steps t0-4..t0-1 */               \
    STEP((t0) + 1);                                                           \
    STEP((t0) + 2);                                                           \
    STEP((t0) + 3);                                                           \
  }

  for (int t0 = 0; t0 < T_; t0 += 8) {
    GROUP(t0, 1, 0);      // write R1 (issued in prologue / prev odd group)
    GROUP(t0 + 4, 0, 1);  // write R0, issue R1
  }
  // epilogue: y_255 into slot 3, then flush the last group
  *(f32x4*)&ys[3][p16][4 * lg] = yp0;
  *(f32x4*)&ys[3][p16][16 + 4 * lg] = yp1;
  Y_FLUSH(T_ - 4);
#undef GROUP
#undef STEP
#undef X_ISSUE
#undef X_WRITE
#undef Y_FLUSH
}

extern "C" void kernel_launch(void* const* d_in, const int* in_sizes, int n_in,
                              void* d_out, int out_size, void* d_ws,
                              size_t ws_size, hipStream_t stream) {
  const float* word = (const float*)d_in[0];
  const float* Wa = (const float*)d_in[1];
  const float* ba = (const float*)d_in[2];
  const float* Wy = (const float*)d_in[3];
  const float* by = (const float*)d_in[4];
  float* out = (float*)d_out;
  rnn_fused<<<dim3(B_ / 16), dim3(64), 0, stream>>>(word, Wa, ba, Wy, by, out);
}

// Round 17
// 87.404 us; speedup vs baseline: 1.7407x; 1.7295x over previous
//
#include <hip/hip_runtime.h>
#include <stdint.h>

// RNN1: B=4096,T=256,E=27,H=64.
// a_{t+1} = tanh(a_t @ Waa^T + x_t @ Wax^T + ba), x_t = word[:,t-1,:] (0 at t=0)
// y[:,t,:] = a_{t+1} @ Wy^T + by
//
// Round 17: 4-WAVE HIDDEN SPLIT. r16 confirmed H2: the step floor is the
// TRANS pipe (32 exp/rcp on ONE SIMD; 3 of 4 SIMDs idle). Block = 256 (4
// waves); wave w owns hidden tile [16w,16w+16) x the block's 16 batch rows:
// per wave/step = 2 chained state MFMAs + 8 trans + 1 zp MFMA. Per-step
// state exchange through LDS: lane (n,hi) of wave w holds hidden 16w+4hi+r
// (C/D layout) -> 2 pkf16 u32 -> ds_write_b64 to sxc[buf][hi][n][2w+u];
// sigma-matched, so next B-frags = two contiguous ds_read_b128. One barrier
// per step, double-buffered sxc (r2-validated pattern: write buf[t&1],
// lgkmcnt, barrier, read buf[t&1]; next step writes the other buffer).
// Off-critical: y_{t-1} on waves 0,1 (old sF); Y-flush on wave 2 (8-step
// deferred, 16-slot ring); x staging on wave 0 (r9 machinery verbatim).
// f16 single-term state (r12-validated numerics); RNE state pack (r14
// lesson: never biased rounding in the recurrence).

#define B_ 4096
#define T_ 256
#define E_ 27
#define H_ 64
#define WROW_ (H_ + E_)  // 91

typedef _Float16 f16x8 __attribute__((ext_vector_type(8)));
typedef float f32x4 __attribute__((ext_vector_type(4)));
typedef unsigned int u32x4 __attribute__((ext_vector_type(4)));
typedef unsigned int u32x2 __attribute__((ext_vector_type(2)));

struct __attribute__((packed)) f4a { float v[4]; };  // 4B-aligned global float4

// RNE f32->f16 pair pack (state + weight prep).
static __device__ __forceinline__ unsigned pkf16(float a, float b) {
  _Float16 ha = (_Float16)a, hb = (_Float16)b;
  unsigned short ua = __builtin_bit_cast(unsigned short, ha);
  unsigned short ub = __builtin_bit_cast(unsigned short, hb);
  return (unsigned)ua | ((unsigned)ub << 16);
}
// RTZ packed f32x2->f16x2 (x-path ONLY: no feedback amplification).
static __device__ __forceinline__ unsigned pkrtz(float a, float b) {
  unsigned r;
  asm("v_cvt_pkrtz_f16_f32 %0, %1, %2" : "=v"(r) : "v"(a), "v"(b));
  return r;
}
static __device__ __forceinline__ float fast_tanh(float z) {
  // tanh(z) = 1 - 2/(exp(2z)+1); exp->inf / ->0 limits give +/-1 correctly
  float e = __expf(2.0f * z);
  float r = __builtin_amdgcn_rcpf(e + 1.0f);
  return __builtin_fmaf(-2.0f, r, 1.0f);
}
static __device__ __forceinline__ f32x4 MFH(u32x4 a, u32x4 b, f32x4 c) {
  return __builtin_amdgcn_mfma_f32_16x16x32_f16(
      __builtin_bit_cast(f16x8, a), __builtin_bit_cast(f16x8, b), c, 0, 0, 0);
}

__global__ __launch_bounds__(256)
__attribute__((amdgpu_waves_per_eu(1, 1))) void rnn_fused(
    const float* __restrict__ word, const float* __restrict__ Wa,
    const float* __restrict__ ba, const float* __restrict__ Wy,
    const float* __restrict__ by, float* __restrict__ out) {
  __shared__ __align__(16) float xs[8][16][36];        // x ring (r9 layout)
  __shared__ __align__(16) float ys[16][16][36];       // y ring, 16 slots
  __shared__ __align__(16) unsigned int sxc[2][4][16][12];  // state exchange

  const int tid = threadIdx.x;
  const int wv = tid >> 6;    // wave = hidden tile [16wv, 16wv+16)
  const int lane = tid & 63;
  const int p16 = lane & 15;  // batch row within block (n) / A-row (m)
  const int lg = lane >> 4;   // k-slot group / D m-group (4lg+r)
  const int rb = (int)blockIdx.x * 16;

  const float* const wbase = word + (size_t)(rb + p16) * (T_ * E_);
  float* const obase = out + (size_t)(rb + p16) * (T_ * E_);

  // zero xs once (slot 0 = x_0 = 0; staged slots overwritten later)
  for (int i = tid; i < 8 * 16 * 36; i += 256) (&xs[0][0][0])[i] = 0.f;

  // ---- per-wave weight fragments (f16), pre-permuted by sigma ----
  u32x4 WH0, WH1, WXw, WY0, WY1;
  f32x4 BAv, BYv;
  {
    const float* base = Wa + (16 * wv + p16) * WROW_;
#pragma unroll
    for (int v = 0; v < 4; ++v) {
      const int j = 2 * v;
      const int c0 = (j < 4) ? (4 * lg + j) : (12 + 4 * lg + j);
      WH0[v] = pkf16(base[c0], base[c0 + 1]);
      WH1[v] = pkf16(base[c0 + 32], base[c0 + 33]);
      const int e0 = 8 * lg + j, e1 = e0 + 1;  // Wax natural k
      const float w0 = (e0 < E_) ? base[H_ + e0] : 0.f;
      const float w1 = (e1 < E_) ? base[H_ + e1] : 0.f;
      WXw[v] = pkf16(w0, w1);
    }
  }
  {
    const int e = 16 * (wv & 1) + p16;  // Wy rows (waves 0,1 use; 2,3 dead)
    const bool valid = (e < E_);
    const float* rp = Wy + e * H_;
#pragma unroll
    for (int v = 0; v < 4; ++v) {
      const int j = 2 * v;
      const int c0 = (j < 4) ? (4 * lg + j) : (12 + 4 * lg + j);
      WY0[v] = pkf16(valid ? rp[c0] : 0.f, valid ? rp[c0 + 1] : 0.f);
      WY1[v] = pkf16(valid ? rp[c0 + 32] : 0.f, valid ? rp[c0 + 33] : 0.f);
    }
  }
#pragma unroll
  for (int r = 0; r < 4; ++r) BAv[r] = ba[16 * wv + 4 * lg + r];
#pragma unroll
  for (int r = 0; r < 4; ++r) {
    const int e = 16 * (wv & 1) + 4 * lg + r;
    BYv[r] = (e < E_) ? by[e] : 0.f;
  }

  // ---- x staging (wave 0 only; r9-validated, double-buffered regs) ----
  f32x4 Rg[2][7];
#define X_ISSUE(ts, P)                                                      \
  {                                                                         \
    const int st_ = (ts) + lg;                                              \
    if (st_ >= 1 && st_ < T_) {                                             \
      const float* p_ = wbase + (st_ - 1) * E_;                             \
      _Pragma("unroll") for (int c = 0; c < 7; ++c) {                       \
        asm volatile("global_load_dwordx4 %0, %1, off"                      \
                     : "=v"(Rg[P][c]) : "v"(p_ + 4 * c) : "memory");        \
      }                                                                     \
    }                                                                       \
  }
#define X_WRITE(ts, P)                                                      \
  {                                                                         \
    asm volatile("s_waitcnt vmcnt(0)" ::: "memory");                        \
    __builtin_amdgcn_sched_barrier(0);                                      \
    const int st_ = (ts) + lg;                                              \
    if (st_ >= 1 && st_ < T_) {                                             \
      float* d_ = &xs[st_ & 7][p16][0];                                     \
      _Pragma("unroll") for (int c = 0; c < 7; ++c)                         \
        *(f32x4*)(d_ + 4 * c) = Rg[P][c];                                   \
    }                                                                       \
    asm volatile("s_waitcnt lgkmcnt(0)" ::: "memory");                      \
    __builtin_amdgcn_sched_barrier(0);                                      \
  }
#define Y_FLUSH(tb)                                                         \
  {                                                                         \
    const float* s_ = &ys[((tb) + lg) & 15][p16][0];                        \
    float* d_ = obase + (size_t)((tb) + lg) * E_;                           \
    _Pragma("unroll") for (int c = 0; c < 6; ++c) {                         \
      f32x4 v_ = *(const f32x4*)(s_ + 4 * c);                               \
      f4a o_;                                                               \
      o_.v[0] = v_[0]; o_.v[1] = v_[1]; o_.v[2] = v_[2]; o_.v[3] = v_[3];   \
      *(f4a*)(d_ + 4 * c) = o_;                                             \
    }                                                                       \
    f32x4 v6_ = *(const f32x4*)(s_ + 24);                                   \
    d_[24] = v6_[0]; d_[25] = v6_[1]; d_[26] = v6_[2];                      \
  }

  // ---- prologue: zero-init visible; wave 0 stages slots 1..3, issues 4..7 --
  if (wv == 0) X_ISSUE(0, 0);
  __syncthreads();
  if (wv == 0) { X_WRITE(0, 0); X_ISSUE(4, 1); }
  __syncthreads();
  f32x4 xc0, xc1;
  {
    const float* xp = &xs[1][p16][8 * lg];  // x_1
    xc0 = *(const f32x4*)xp;
    xc1 = *(const f32x4*)(xp + 4);
  }

  // ---- loop-carried: sF = a_t (f16 sigma B-frags, full state, all waves);
  // zp = ba + WX*x_t for this wave's tile (x_0 = 0 -> ba) ----
  u32x4 sF0 = {0u, 0u, 0u, 0u}, sF1 = sF0;
  f32x4 zp = BAv;

#define STEP(t)                                                               \
  {                                                                           \
    /* critical: 2 chained MFMAs -> tanh x4 -> pack -> exchange */            \
    f32x4 d_ = MFH(WH0, sF0, zp);                                             \
    d_ = MFH(WH1, sF1, d_);                                                   \
    /* off-path (fills MFMA shadow): y_{t-1} on OLD sF (waves 0,1) */         \
    if (wv < 2) {                                                             \
      f32x4 yv = MFH(WY1, sF1, MFH(WY0, sF0, BYv));                           \
      *(f32x4*)&ys[((t) + 15) & 15][p16][(wv & 1) * 16 + 4 * lg] = yv;        \
    }                                                                         \
    /* zp for step t+1 (xfn = x_{t+1}); then prefetch x_{t+2} */              \
    u32x4 xfn;                                                                \
    xfn[0] = pkrtz(xc0[0], xc0[1]);                                           \
    xfn[1] = pkrtz(xc0[2], xc0[3]);                                           \
    xfn[2] = pkrtz(xc1[0], xc1[1]);                                           \
    xfn[3] = pkrtz(xc1[2], xc1[3]);                                           \
    zp = MFH(WXw, xfn, BAv);                                                  \
    if ((t) + 2 < T_) {                                                       \
      const float* xp_ = &xs[((t) + 2) & 7][p16][8 * lg];                     \
      xc0 = *(const f32x4*)xp_;                                               \
      xc1 = *(const f32x4*)(xp_ + 4);                                         \
    }                                                                         \
    /* tanh (8 trans on THIS SIMD only) + RNE pack + exchange write */        \
    const float t0_ = fast_tanh(d_[0]);                                       \
    const float t1_ = fast_tanh(d_[1]);                                       \
    const float t2_ = fast_tanh(d_[2]);                                       \
    const float t3_ = fast_tanh(d_[3]);                                       \
    u32x2 pk_;                                                                \
    pk_[0] = pkf16(t0_, t1_);                                                 \
    pk_[1] = pkf16(t2_, t3_);                                                 \
    *(u32x2*)&sxc[(t) & 1][lg][p16][2 * wv] = pk_;                            \
    asm volatile("s_waitcnt lgkmcnt(0)" ::: "memory");                        \
    __builtin_amdgcn_sched_barrier(0);                                        \
    __builtin_amdgcn_s_barrier();                                             \
    __builtin_amdgcn_sched_barrier(0);                                        \
    /* read back full new state (two contiguous b128) */                      \
    sF0 = *(const u32x4*)&sxc[(t) & 1][lg][p16][0];                           \
    sF1 = *(const u32x4*)&sxc[(t) & 1][lg][p16][4];                           \
  }

#define GROUP(t0, PW, PI)                                                     \
  {                                                                           \
    asm volatile("" : "+a"(WH0), "+a"(WH1), "+a"(WXw), "+a"(WY0), "+a"(WY1)); \
    asm volatile("" : "+v"(BAv), "+v"(BYv));                                  \
    if (wv == 0) { X_WRITE((t0) + 4, PW); X_ISSUE((t0) + 8, PI); }            \
    if (wv == 2 && (t0) >= 8) Y_FLUSH((t0)-8);                                \
    STEP(t0);                                                                 \
    STEP((t0) + 1);                                                           \
    STEP((t0) + 2);                                                           \
    STEP((t0) + 3);                                                           \
  }

  for (int t0 = 0; t0 < T_; t0 += 8) {
    GROUP(t0, 1, 0);      // write R1 (issued in prologue / prev odd group)
    GROUP(t0 + 4, 0, 1);  // write R0, issue R1
  }
  // epilogue: y_255 from final state; flush last 8 steps
  if (wv < 2) {
    f32x4 yv = MFH(WY1, sF1, MFH(WY0, sF0, BYv));
    *(f32x4*)&ys[15][p16][(wv & 1) * 16 + 4 * lg] = yv;
  }
  asm volatile("s_waitcnt lgkmcnt(0)" ::: "memory");
  __builtin_amdgcn_s_barrier();
  if (wv == 2) {
    Y_FLUSH(T_ - 8);
    Y_FLUSH(T_ - 4);
  }
#undef GROUP
#undef STEP
#undef X_ISSUE
#undef X_WRITE
#undef Y_FLUSH
}

extern "C" void kernel_launch(void* const* d_in, const int* in_sizes, int n_in,
                              void* d_out, int out_size, void* d_ws,
                              size_t ws_size, hipStream_t stream) {
  const float* word = (const float*)d_in[0];
  const float* Wa = (const float*)d_in[1];
  const float* ba = (const float*)d_in[2];
  const float* Wy = (const float*)d_in[3];
  const float* by = (const float*)d_in[4];
  float* out = (float*)d_out;
  rnn_fused<<<dim3(B_ / 16), dim3(256), 0, stream>>>(word, Wa, ba, Wy, by, out);
}